// Round 2
// baseline (1296.767 us; speedup 1.0000x reference)
//
#include <hip/hip_runtime.h>

#define N_NODESC 50000
#define N_EDGESC 400000
#define N_GRAPHSC 128
#define IN_DIMC 768
#define HIDC 128
#define NCLSC 11
#define BN_EPSC 1e-5f
#define NB_AGG 8

typedef __bf16 bf16_t;
typedef __bf16 bf16x8 __attribute__((ext_vector_type(8)));
typedef float f32x4 __attribute__((ext_vector_type(4)));

__device__ inline f32x4 mfma_16x16x32_bf16(bf16x8 a, bf16x8 b, f32x4 c) {
    return __builtin_amdgcn_mfma_f32_16x16x32_bf16(a, b, c, 0, 0, 0);
}

// C[M,256] = BN?(A)[M,K] @ [Bl;Br]^T.  A fp32 row-major; Bl/Br [128,K] fp32.
// APPLY_BN: A-staging applies relu(a*scale[ch]+shift[ch]) with ch = column of A.
// blockIdx.y selects Bl (cols 0..127) or Br (cols 128..255).
template<bool APPLY_BN>
__global__ __launch_bounds__(256) void gemm_kernel(const float* __restrict__ A,
                                                   const float* __restrict__ Bl,
                                                   const float* __restrict__ Br,
                                                   const float* __restrict__ sc,
                                                   float* __restrict__ C, int M, int K)
{
    __shared__ bf16_t As[128][40];   // pad 32->40: 16B-aligned b128 reads, 2-way banks (free)
    __shared__ bf16_t Bs[128][40];

    const int t  = threadIdx.x;
    const int m0 = blockIdx.x * 128;
    const int n0 = blockIdx.y * 128;
    const float* Bsel = (blockIdx.y == 0) ? Bl : Br;

    const int r  = t >> 3;         // staging row 0..31 (+p*32)
    const int c4 = (t & 7) * 4;    // staging col 0,4,...,28

    const int wid  = t >> 6;
    const int lane = t & 63;
    const int wm   = (wid >> 1) * 64;
    const int wn   = (wid & 1) * 64;
    const int l16  = lane & 15;
    const int quad = lane >> 4;

    f32x4 acc[4][4] = {};

    for (int k0 = 0; k0 < K; k0 += 32) {
#pragma unroll
        for (int p = 0; p < 4; p++) {
            int row = r + p * 32;
            int am  = m0 + row; if (am > M - 1) am = M - 1;   // clamp (garbage rows never stored)
            float4 v = *(const float4*)&A[(size_t)am * K + k0 + c4];
            if (APPLY_BN) {
                float4 s4 = *(const float4*)&sc[k0 + c4];
                float4 h4 = *(const float4*)&sc[HIDC + k0 + c4];
                v.x = fmaxf(fmaf(v.x, s4.x, h4.x), 0.0f);
                v.y = fmaxf(fmaf(v.y, s4.y, h4.y), 0.0f);
                v.z = fmaxf(fmaf(v.z, s4.z, h4.z), 0.0f);
                v.w = fmaxf(fmaf(v.w, s4.w, h4.w), 0.0f);
            }
            As[row][c4 + 0] = (bf16_t)v.x; As[row][c4 + 1] = (bf16_t)v.y;
            As[row][c4 + 2] = (bf16_t)v.z; As[row][c4 + 3] = (bf16_t)v.w;
            float4 w = *(const float4*)&Bsel[(size_t)row * K + k0 + c4];
            Bs[row][c4 + 0] = (bf16_t)w.x; Bs[row][c4 + 1] = (bf16_t)w.y;
            Bs[row][c4 + 2] = (bf16_t)w.z; Bs[row][c4 + 3] = (bf16_t)w.w;
        }
        __syncthreads();

        bf16x8 af[4], bfr[4];
#pragma unroll
        for (int i = 0; i < 4; i++)
            af[i] = *(const bf16x8*)&As[wm + i * 16 + l16][quad * 8];
#pragma unroll
        for (int j = 0; j < 4; j++)
            bfr[j] = *(const bf16x8*)&Bs[wn + j * 16 + l16][quad * 8];
#pragma unroll
        for (int i = 0; i < 4; i++)
#pragma unroll
            for (int j = 0; j < 4; j++)
                acc[i][j] = mfma_16x16x32_bf16(af[i], bfr[j], acc[i][j]);
        __syncthreads();
    }

    // C/D layout (m89-verified): col = lane&15, row = quad*4 + reg
#pragma unroll
    for (int i = 0; i < 4; i++) {
        int rowb = m0 + wm + i * 16 + quad * 4;
#pragma unroll
        for (int j = 0; j < 4; j++) {
            int col = n0 + wn + j * 16 + l16;
#pragma unroll
            for (int rr = 0; rr < 4; rr++) {
                int row = rowb + rr;
                if (row < M) C[(size_t)row * 256 + col] = acc[i][j][rr];
            }
        }
    }
}

// ---------- CSR build ----------
__global__ void degi_kernel(const int* __restrict__ ei, int* __restrict__ degi) {
    int e = blockIdx.x * blockDim.x + threadIdx.x;
    if (e < N_EDGESC) atomicAdd(&degi[ei[N_EDGESC + e]], 1);
}

// single block, 1024 threads: chunked exclusive scan of degi -> rowptr, cursor
__global__ __launch_bounds__(1024) void scan_kernel(const int* __restrict__ degi,
                                                    int* __restrict__ rowptr,
                                                    int* __restrict__ cursor)
{
    __shared__ int part[1024];
    const int t = threadIdx.x;
    const int CH = (N_NODESC + 1023) / 1024;   // 49
    const int base = t * CH;
    int sum = 0;
    for (int i = 0; i < CH; i++) {
        int idx = base + i;
        if (idx < N_NODESC) sum += degi[idx];
    }
    part[t] = sum;
    __syncthreads();
    for (int off = 1; off < 1024; off <<= 1) {
        int v = (t >= off) ? part[t - off] : 0;
        __syncthreads();
        part[t] += v;
        __syncthreads();
    }
    int run = part[t] - sum;   // exclusive offset of this thread's chunk
    for (int i = 0; i < CH; i++) {
        int idx = base + i;
        if (idx < N_NODESC) {
            int d = degi[idx];
            rowptr[idx] = run;
            cursor[idx] = run;
            run += d;
        }
    }
    if (t == 1023) rowptr[N_NODESC] = part[1023];
}

__global__ void fill_kernel(const int* __restrict__ ei, int* __restrict__ cursor,
                            int* __restrict__ col) {
    int e = blockIdx.x * blockDim.x + threadIdx.x;
    if (e >= N_EDGESC) return;
    int d = ei[N_EDGESC + e];
    int pos = atomicAdd(&cursor[d], 1);
    col[pos] = ei[e];
}

// ---------- fused CSR-gather mean-agg + bias + Pr + BN partial sums ----------
__global__ __launch_bounds__(128) void agg_combine_kernel(const int* __restrict__ rowptr,
                                                          const int* __restrict__ col,
                                                          const float* __restrict__ P,
                                                          const float* __restrict__ bias,
                                                          float* __restrict__ Hpre,
                                                          float* __restrict__ stats, int M)
{
    const int c = threadIdx.x;
    const float b = bias[c];
    float s = 0.f, s2 = 0.f;
    const int n0 = blockIdx.x * NB_AGG;
    for (int rr = 0; rr < NB_AGG; rr++) {
        int n = n0 + rr;
        if (n >= M) break;
        int lo = rowptr[n], hi = rowptr[n + 1];
        float a = 0.f;
        for (int e = lo; e < hi; e++) {
            int src = col[e];                       // same addr all lanes -> broadcast
            a += P[(size_t)src * 256 + c];          // coalesced 512B row
        }
        int d = hi - lo;
        float inv = 1.0f / (float)(d > 0 ? d : 1);
        float pre = a * inv + b + P[(size_t)n * 256 + HIDC + c];
        Hpre[(size_t)n * HIDC + c] = pre;
        s += pre; s2 += pre * pre;
    }
    atomicAdd(&stats[c], s);
    atomicAdd(&stats[HIDC + c], s2);
}

// stats -> per-channel scale/shift:  y = x*scale + shift
__global__ __launch_bounds__(128) void finalize_kernel(const float* __restrict__ stats,
                                                       const float* __restrict__ g,
                                                       const float* __restrict__ be,
                                                       float* __restrict__ sc, int M)
{
    int c = threadIdx.x;
    float invM = 1.0f / (float)M;
    float mean = stats[c] * invM;
    float var  = stats[HIDC + c] * invM - mean * mean;
    float s = rsqrtf(var + BN_EPSC) * g[c];
    sc[c] = s;
    sc[HIDC + c] = be[c] - mean * s;
}

// pool with BN3 applied per element (scale>0 not assumed: transform precedes max)
__global__ __launch_bounds__(128) void pool_kernel(const float* __restrict__ Hpre,
                                                   const float* __restrict__ sc,
                                                   const int* __restrict__ batch,
                                                   float* __restrict__ pooled, int M)
{
    int gph = blockIdx.x;
    int c   = threadIdx.x;
    float s = sc[c], h = sc[HIDC + c];
    int lo = 0, hi = M;
    while (lo < hi) { int m = (lo + hi) >> 1; if (batch[m] < gph) lo = m + 1; else hi = m; }
    int lo2 = lo, hi2 = M;
    while (lo2 < hi2) { int m = (lo2 + hi2) >> 1; if (batch[m] < gph + 1) lo2 = m + 1; else hi2 = m; }
    float mx = -INFINITY;
    for (int rr = lo; rr < lo2; rr++)
        mx = fmaxf(mx, fmaf(Hpre[(size_t)rr * HIDC + c], s, h));
    pooled[gph * HIDC + c] = mx;
}

__global__ __launch_bounds__(128) void final_kernel(const float* __restrict__ pooled,
                                                    const float* __restrict__ W,
                                                    const float* __restrict__ bl,
                                                    float* __restrict__ out)
{
    __shared__ float sp[HIDC];
    int gph = blockIdx.x;
    int t   = threadIdx.x;
    sp[t] = pooled[gph * HIDC + t];
    __syncthreads();
    if (t < NCLSC) {
        float acc = bl[t];
        for (int c = 0; c < HIDC; c++) acc += sp[c] * W[t * HIDC + c];
        out[gph * NCLSC + t] = acc;
    }
}

extern "C" void kernel_launch(void* const* d_in, const int* in_sizes, int n_in,
                              void* d_out, int out_size, void* d_ws, size_t ws_size,
                              hipStream_t stream)
{
    const float* x     = (const float*)d_in[0];
    const int*   ei    = (const int*)d_in[1];
    const int*   batch = (const int*)d_in[2];
    const float* W1l = (const float*)d_in[3];
    const float* b1  = (const float*)d_in[4];
    const float* W1r = (const float*)d_in[5];
    const float* g1  = (const float*)d_in[6];
    const float* be1 = (const float*)d_in[7];
    const float* W2l = (const float*)d_in[8];
    const float* b2  = (const float*)d_in[9];
    const float* W2r = (const float*)d_in[10];
    const float* g2  = (const float*)d_in[11];
    const float* be2 = (const float*)d_in[12];
    const float* W3l = (const float*)d_in[13];
    const float* b3  = (const float*)d_in[14];
    const float* W3r = (const float*)d_in[15];
    const float* g3  = (const float*)d_in[16];
    const float* be3 = (const float*)d_in[17];
    const float* Wlin = (const float*)d_in[18];
    const float* blin = (const float*)d_in[19];

    const int M = N_NODESC;

    // workspace carve
    char* w = (char*)d_ws;
    float* P      = (float*)w;  w += (size_t)M * 256 * 4;          // 51.2 MB
    float* Hpre   = (float*)w;  w += (size_t)M * HIDC * 4;         // 25.6 MB
    int*   rowptr = (int*)w;    w += (size_t)(M + 1) * 4;
    int*   col    = (int*)w;    w += (size_t)N_EDGESC * 4;
    int*   cursor = (int*)w;    w += (size_t)M * 4;
    int*   degi   = (int*)w;    w += (size_t)M * 4;
    float* stats  = (float*)w;  w += 256 * 4;
    float* sc     = (float*)w;  w += 256 * 4;
    float* pooled = (float*)w;  w += (size_t)N_GRAPHSC * HIDC * 4;

    const dim3 gemm_grid((M + 127) / 128, 2);
    const int agg_blocks = (M + NB_AGG - 1) / NB_AGG;

    // ---- CSR build (per call: ws is re-poisoned) ----
    hipMemsetAsync(degi, 0, (size_t)M * 4, stream);
    degi_kernel<<<(N_EDGESC + 255) / 256, 256, 0, stream>>>(ei, degi);
    scan_kernel<<<1, 1024, 0, stream>>>(degi, rowptr, cursor);
    fill_kernel<<<(N_EDGESC + 255) / 256, 256, 0, stream>>>(ei, cursor, col);

    // ---- layer 1 (K = 768, no BN on input) ----
    gemm_kernel<false><<<gemm_grid, 256, 0, stream>>>(x, W1l, W1r, nullptr, P, M, IN_DIMC);
    hipMemsetAsync(stats, 0, 256 * 4, stream);
    agg_combine_kernel<<<agg_blocks, 128, 0, stream>>>(rowptr, col, P, b1, Hpre, stats, M);
    finalize_kernel<<<1, 128, 0, stream>>>(stats, g1, be1, sc, M);

    // ---- layer 2 (K = 128, BN1+ReLU fused into A-staging) ----
    gemm_kernel<true><<<gemm_grid, 256, 0, stream>>>(Hpre, W2l, W2r, sc, P, M, HIDC);
    hipMemsetAsync(stats, 0, 256 * 4, stream);
    agg_combine_kernel<<<agg_blocks, 128, 0, stream>>>(rowptr, col, P, b2, Hpre, stats, M);
    finalize_kernel<<<1, 128, 0, stream>>>(stats, g2, be2, sc, M);

    // ---- layer 3 (K = 128, BN2+ReLU fused into A-staging) ----
    gemm_kernel<true><<<gemm_grid, 256, 0, stream>>>(Hpre, W3l, W3r, sc, P, M, HIDC);
    hipMemsetAsync(stats, 0, 256 * 4, stream);
    agg_combine_kernel<<<agg_blocks, 128, 0, stream>>>(rowptr, col, P, b3, Hpre, stats, M);
    finalize_kernel<<<1, 128, 0, stream>>>(stats, g3, be3, sc, M);

    // ---- pool (BN3 fused) + head ----
    pool_kernel<<<N_GRAPHSC, 128, 0, stream>>>(Hpre, sc, batch, pooled, M);
    final_kernel<<<N_GRAPHSC, 128, 0, stream>>>(pooled, Wlin, blin, (float*)d_out);
}

// Round 3
// 1077.731 us; speedup vs baseline: 1.2032x; 1.2032x over previous
//
#include <hip/hip_runtime.h>

#define N_NODESC 50000
#define N_EDGESC 400000
#define N_GRAPHSC 128
#define IN_DIMC 768
#define HIDC 128
#define NCLSC 11
#define BN_EPSC 1e-5f
#define NB_AGG 8

typedef __bf16 bf16_t;
typedef __bf16 bf16x8 __attribute__((ext_vector_type(8)));
typedef float f32x4 __attribute__((ext_vector_type(4)));

__device__ inline f32x4 mfma_16x16x32_bf16(bf16x8 a, bf16x8 b, f32x4 c) {
    return __builtin_amdgcn_mfma_f32_16x16x32_bf16(a, b, c, 0, 0, 0);
}

// [Cl | Cr] = BN?(A)[M,K] @ [Bl;Br]^T.  A fp32 row-major; Bl/Br [128,K] fp32.
// blockIdx.y==0 -> writes Cl as bf16 [M,128] (aggregation operand);
// blockIdx.y==1 -> writes Cr as fp32 [M,128] (residual/self term).
// APPLY_BN: A-staging applies relu(a*scale[ch]+shift[ch]) with ch = column of A.
template<bool APPLY_BN>
__global__ __launch_bounds__(256) void gemm_kernel(const float* __restrict__ A,
                                                   const float* __restrict__ Bl,
                                                   const float* __restrict__ Br,
                                                   const float* __restrict__ sc,
                                                   bf16_t* __restrict__ Cl,
                                                   float* __restrict__ Cr, int M, int K)
{
    __shared__ bf16_t As[128][40];   // pad 32->40: 16B-aligned b128 reads, 2-way banks (free)
    __shared__ bf16_t Bs[128][40];

    const int t  = threadIdx.x;
    const int m0 = blockIdx.x * 128;
    const float* Bsel = (blockIdx.y == 0) ? Bl : Br;

    const int r  = t >> 3;         // staging row 0..31 (+p*32)
    const int c4 = (t & 7) * 4;    // staging col 0,4,...,28

    const int wid  = t >> 6;
    const int lane = t & 63;
    const int wm   = (wid >> 1) * 64;
    const int wn   = (wid & 1) * 64;
    const int l16  = lane & 15;
    const int quad = lane >> 4;

    f32x4 acc[4][4] = {};

    for (int k0 = 0; k0 < K; k0 += 32) {
#pragma unroll
        for (int p = 0; p < 4; p++) {
            int row = r + p * 32;
            int am  = m0 + row; if (am > M - 1) am = M - 1;   // clamp (garbage rows never stored)
            float4 v = *(const float4*)&A[(size_t)am * K + k0 + c4];
            if (APPLY_BN) {
                float4 s4 = *(const float4*)&sc[k0 + c4];
                float4 h4 = *(const float4*)&sc[HIDC + k0 + c4];
                v.x = fmaxf(fmaf(v.x, s4.x, h4.x), 0.0f);
                v.y = fmaxf(fmaf(v.y, s4.y, h4.y), 0.0f);
                v.z = fmaxf(fmaf(v.z, s4.z, h4.z), 0.0f);
                v.w = fmaxf(fmaf(v.w, s4.w, h4.w), 0.0f);
            }
            As[row][c4 + 0] = (bf16_t)v.x; As[row][c4 + 1] = (bf16_t)v.y;
            As[row][c4 + 2] = (bf16_t)v.z; As[row][c4 + 3] = (bf16_t)v.w;
            float4 w = *(const float4*)&Bsel[(size_t)row * K + k0 + c4];
            Bs[row][c4 + 0] = (bf16_t)w.x; Bs[row][c4 + 1] = (bf16_t)w.y;
            Bs[row][c4 + 2] = (bf16_t)w.z; Bs[row][c4 + 3] = (bf16_t)w.w;
        }
        __syncthreads();

        bf16x8 af[4], bfr[4];
#pragma unroll
        for (int i = 0; i < 4; i++)
            af[i] = *(const bf16x8*)&As[wm + i * 16 + l16][quad * 8];
#pragma unroll
        for (int j = 0; j < 4; j++)
            bfr[j] = *(const bf16x8*)&Bs[wn + j * 16 + l16][quad * 8];
#pragma unroll
        for (int i = 0; i < 4; i++)
#pragma unroll
            for (int j = 0; j < 4; j++)
                acc[i][j] = mfma_16x16x32_bf16(af[i], bfr[j], acc[i][j]);
        __syncthreads();
    }

    // C/D layout (m89-verified): col = lane&15, row = quad*4 + reg
#pragma unroll
    for (int i = 0; i < 4; i++) {
        int rowb = m0 + wm + i * 16 + quad * 4;
#pragma unroll
        for (int j = 0; j < 4; j++) {
            int colh = wn + j * 16 + l16;   // 0..127 within the half
#pragma unroll
            for (int rr = 0; rr < 4; rr++) {
                int row = rowb + rr;
                if (row < M) {
                    if (blockIdx.y == 0) Cl[(size_t)row * HIDC + colh] = (bf16_t)acc[i][j][rr];
                    else                 Cr[(size_t)row * HIDC + colh] = acc[i][j][rr];
                }
            }
        }
    }
}

// ---------- CSR build ----------
__global__ void degi_kernel(const int* __restrict__ ei, int* __restrict__ degi) {
    int e = blockIdx.x * blockDim.x + threadIdx.x;
    if (e < N_EDGESC) atomicAdd(&degi[ei[N_EDGESC + e]], 1);
}

// single block, 1024 threads: chunked exclusive scan of degi -> rowptr, cursor
__global__ __launch_bounds__(1024) void scan_kernel(const int* __restrict__ degi,
                                                    int* __restrict__ rowptr,
                                                    int* __restrict__ cursor)
{
    __shared__ int part[1024];
    const int t = threadIdx.x;
    const int CH = (N_NODESC + 1023) / 1024;   // 49
    const int base = t * CH;
    int sum = 0;
    for (int i = 0; i < CH; i++) {
        int idx = base + i;
        if (idx < N_NODESC) sum += degi[idx];
    }
    part[t] = sum;
    __syncthreads();
    for (int off = 1; off < 1024; off <<= 1) {
        int v = (t >= off) ? part[t - off] : 0;
        __syncthreads();
        part[t] += v;
        __syncthreads();
    }
    int run = part[t] - sum;   // exclusive offset of this thread's chunk
    for (int i = 0; i < CH; i++) {
        int idx = base + i;
        if (idx < N_NODESC) {
            int d = degi[idx];
            rowptr[idx] = run;
            cursor[idx] = run;
            run += d;
        }
    }
    if (t == 1023) rowptr[N_NODESC] = part[1023];
}

__global__ void fill_kernel(const int* __restrict__ ei, int* __restrict__ cursor,
                            int* __restrict__ col) {
    int e = blockIdx.x * blockDim.x + threadIdx.x;
    if (e >= N_EDGESC) return;
    int d = ei[N_EDGESC + e];
    int pos = atomicAdd(&cursor[d], 1);
    col[pos] = ei[e];
}

// ---------- fused CSR-gather mean-agg + bias + Pr + BN partial sums ----------
// 8-way edge unroll: 8 independent bf16 row-loads in flight per wave per round.
__global__ __launch_bounds__(128) void agg_combine_kernel(const int* __restrict__ rowptr,
                                                          const int* __restrict__ col,
                                                          const bf16_t* __restrict__ Plb,
                                                          const float* __restrict__ Pr,
                                                          const float* __restrict__ bias,
                                                          float* __restrict__ Hpre,
                                                          float* __restrict__ stats, int M)
{
    const int c = threadIdx.x;
    const float b = bias[c];
    float s = 0.f, s2 = 0.f;
    const int n0 = blockIdx.x * NB_AGG;
    for (int rr = 0; rr < NB_AGG; rr++) {
        int n = n0 + rr;
        if (n >= M) break;
        int lo = rowptr[n], hi = rowptr[n + 1];
        float a = 0.f;
        for (int e = lo; e < hi; e += 8) {
            int rem = hi - e;
            int idx[8];
#pragma unroll
            for (int j = 0; j < 8; j++) {
                int ee = e + j; if (ee > hi - 1) ee = hi - 1;
                idx[j] = col[ee];                       // 8 independent broadcast loads
            }
            float v[8];
#pragma unroll
            for (int j = 0; j < 8; j++)
                v[j] = (float)Plb[(size_t)idx[j] * HIDC + c];   // 8 loads in flight
#pragma unroll
            for (int j = 0; j < 8; j++)
                if (j < rem) a += v[j];                 // wave-uniform predicate
        }
        int d = hi - lo;
        float inv = 1.0f / (float)(d > 0 ? d : 1);
        float pre = fmaf(a, inv, b) + Pr[(size_t)n * HIDC + c];
        Hpre[(size_t)n * HIDC + c] = pre;
        s += pre; s2 += pre * pre;
    }
    atomicAdd(&stats[c], s);
    atomicAdd(&stats[HIDC + c], s2);
}

// stats -> per-channel scale/shift:  y = x*scale + shift
__global__ __launch_bounds__(128) void finalize_kernel(const float* __restrict__ stats,
                                                       const float* __restrict__ g,
                                                       const float* __restrict__ be,
                                                       float* __restrict__ sc, int M)
{
    int c = threadIdx.x;
    float invM = 1.0f / (float)M;
    float mean = stats[c] * invM;
    float var  = stats[HIDC + c] * invM - mean * mean;
    float s = rsqrtf(var + BN_EPSC) * g[c];
    sc[c] = s;
    sc[HIDC + c] = be[c] - mean * s;
}

// pool with BN3 applied per element (transform precedes max; sign-safe)
__global__ __launch_bounds__(128) void pool_kernel(const float* __restrict__ Hpre,
                                                   const float* __restrict__ sc,
                                                   const int* __restrict__ batch,
                                                   float* __restrict__ pooled, int M)
{
    int gph = blockIdx.x;
    int c   = threadIdx.x;
    float s = sc[c], h = sc[HIDC + c];
    int lo = 0, hi = M;
    while (lo < hi) { int m = (lo + hi) >> 1; if (batch[m] < gph) lo = m + 1; else hi = m; }
    int lo2 = lo, hi2 = M;
    while (lo2 < hi2) { int m = (lo2 + hi2) >> 1; if (batch[m] < gph + 1) lo2 = m + 1; else hi2 = m; }
    float mx = -INFINITY;
    for (int rr = lo; rr < lo2; rr++)
        mx = fmaxf(mx, fmaf(Hpre[(size_t)rr * HIDC + c], s, h));
    pooled[gph * HIDC + c] = mx;
}

__global__ __launch_bounds__(128) void final_kernel(const float* __restrict__ pooled,
                                                    const float* __restrict__ W,
                                                    const float* __restrict__ bl,
                                                    float* __restrict__ out)
{
    __shared__ float sp[HIDC];
    int gph = blockIdx.x;
    int t   = threadIdx.x;
    sp[t] = pooled[gph * HIDC + t];
    __syncthreads();
    if (t < NCLSC) {
        float acc = bl[t];
        for (int c = 0; c < HIDC; c++) acc += sp[c] * W[t * HIDC + c];
        out[gph * NCLSC + t] = acc;
    }
}

extern "C" void kernel_launch(void* const* d_in, const int* in_sizes, int n_in,
                              void* d_out, int out_size, void* d_ws, size_t ws_size,
                              hipStream_t stream)
{
    const float* x     = (const float*)d_in[0];
    const int*   ei    = (const int*)d_in[1];
    const int*   batch = (const int*)d_in[2];
    const float* W1l = (const float*)d_in[3];
    const float* b1  = (const float*)d_in[4];
    const float* W1r = (const float*)d_in[5];
    const float* g1  = (const float*)d_in[6];
    const float* be1 = (const float*)d_in[7];
    const float* W2l = (const float*)d_in[8];
    const float* b2  = (const float*)d_in[9];
    const float* W2r = (const float*)d_in[10];
    const float* g2  = (const float*)d_in[11];
    const float* be2 = (const float*)d_in[12];
    const float* W3l = (const float*)d_in[13];
    const float* b3  = (const float*)d_in[14];
    const float* W3r = (const float*)d_in[15];
    const float* g3  = (const float*)d_in[16];
    const float* be3 = (const float*)d_in[17];
    const float* Wlin = (const float*)d_in[18];
    const float* blin = (const float*)d_in[19];

    const int M = N_NODESC;

    // workspace carve (all 16B-aligned: sizes are multiples of 16)
    char* w = (char*)d_ws;
    bf16_t* Plb  = (bf16_t*)w;  w += (size_t)M * HIDC * 2;   // 12.8 MB
    float* Pr    = (float*)w;   w += (size_t)M * HIDC * 4;   // 25.6 MB
    float* Hpre  = (float*)w;   w += (size_t)M * HIDC * 4;   // 25.6 MB
    int*   rowptr= (int*)w;     w += (size_t)(M + 16) * 4;
    int*   col   = (int*)w;     w += (size_t)N_EDGESC * 4;
    int*   cursor= (int*)w;     w += (size_t)M * 4;
    int*   degi  = (int*)w;     w += (size_t)M * 4;
    float* stats = (float*)w;   w += 256 * 4;
    float* sc    = (float*)w;   w += 256 * 4;
    float* pooled= (float*)w;   w += (size_t)N_GRAPHSC * HIDC * 4;

    const dim3 gemm_grid((M + 127) / 128, 2);
    const int agg_blocks = (M + NB_AGG - 1) / NB_AGG;

    // ---- CSR build (per call: ws is re-poisoned) ----
    hipMemsetAsync(degi, 0, (size_t)M * 4, stream);
    degi_kernel<<<(N_EDGESC + 255) / 256, 256, 0, stream>>>(ei, degi);
    scan_kernel<<<1, 1024, 0, stream>>>(degi, rowptr, cursor);
    fill_kernel<<<(N_EDGESC + 255) / 256, 256, 0, stream>>>(ei, cursor, col);

    // ---- layer 1 (K = 768, no BN on input) ----
    gemm_kernel<false><<<gemm_grid, 256, 0, stream>>>(x, W1l, W1r, nullptr, Plb, Pr, M, IN_DIMC);
    hipMemsetAsync(stats, 0, 256 * 4, stream);
    agg_combine_kernel<<<agg_blocks, 128, 0, stream>>>(rowptr, col, Plb, Pr, b1, Hpre, stats, M);
    finalize_kernel<<<1, 128, 0, stream>>>(stats, g1, be1, sc, M);

    // ---- layer 2 (K = 128, BN1+ReLU fused into A-staging) ----
    gemm_kernel<true><<<gemm_grid, 256, 0, stream>>>(Hpre, W2l, W2r, sc, Plb, Pr, M, HIDC);
    hipMemsetAsync(stats, 0, 256 * 4, stream);
    agg_combine_kernel<<<agg_blocks, 128, 0, stream>>>(rowptr, col, Plb, Pr, b2, Hpre, stats, M);
    finalize_kernel<<<1, 128, 0, stream>>>(stats, g2, be2, sc, M);

    // ---- layer 3 (K = 128, BN2+ReLU fused into A-staging) ----
    gemm_kernel<true><<<gemm_grid, 256, 0, stream>>>(Hpre, W3l, W3r, sc, Plb, Pr, M, HIDC);
    hipMemsetAsync(stats, 0, 256 * 4, stream);
    agg_combine_kernel<<<agg_blocks, 128, 0, stream>>>(rowptr, col, Plb, Pr, b3, Hpre, stats, M);
    finalize_kernel<<<1, 128, 0, stream>>>(stats, g3, be3, sc, M);

    // ---- pool (BN3 fused) + head ----
    pool_kernel<<<N_GRAPHSC, 128, 0, stream>>>(Hpre, sc, batch, pooled, M);
    final_kernel<<<N_GRAPHSC, 128, 0, stream>>>(pooled, Wlin, blin, (float*)d_out);
}

// Round 4
// 711.502 us; speedup vs baseline: 1.8226x; 1.5147x over previous
//
#include <hip/hip_runtime.h>

#define N_NODESC 50000
#define N_EDGESC 400000
#define N_GRAPHSC 128
#define IN_DIMC 768
#define HIDC 128
#define NCLSC 11
#define BN_EPSC 1e-5f
#define NB_AGG 8
#define NREP 64   // stats atomic replicas: 6250 blocks / 64 -> ~98-deep chains per address

typedef __bf16 bf16_t;
typedef __bf16 bf16x8 __attribute__((ext_vector_type(8)));
typedef float f32x4 __attribute__((ext_vector_type(4)));

__device__ inline f32x4 mfma_16x16x32_bf16(bf16x8 a, bf16x8 b, f32x4 c) {
    return __builtin_amdgcn_mfma_f32_16x16x32_bf16(a, b, c, 0, 0, 0);
}

// [Cl | Cr] = BN?(A)[M,K] @ [Bl;Br]^T.  A fp32 row-major; Bl/Br [128,K] fp32.
// blockIdx.y==0 -> writes Cl as bf16 [M,128] (aggregation operand);
// blockIdx.y==1 -> writes Cr as fp32 [M,128] (residual/self term).
// APPLY_BN: A-staging applies relu(a*scale[ch]+shift[ch]) with ch = column of A.
template<bool APPLY_BN>
__global__ __launch_bounds__(256) void gemm_kernel(const float* __restrict__ A,
                                                   const float* __restrict__ Bl,
                                                   const float* __restrict__ Br,
                                                   const float* __restrict__ sc,
                                                   bf16_t* __restrict__ Cl,
                                                   float* __restrict__ Cr, int M, int K)
{
    __shared__ bf16_t As[128][40];   // pad 32->40: 16B-aligned b128 reads, 2-way banks (free)
    __shared__ bf16_t Bs[128][40];

    const int t  = threadIdx.x;
    const int m0 = blockIdx.x * 128;
    const float* Bsel = (blockIdx.y == 0) ? Bl : Br;

    const int r  = t >> 3;         // staging row 0..31 (+p*32)
    const int c4 = (t & 7) * 4;    // staging col 0,4,...,28

    const int wid  = t >> 6;
    const int lane = t & 63;
    const int wm   = (wid >> 1) * 64;
    const int wn   = (wid & 1) * 64;
    const int l16  = lane & 15;
    const int quad = lane >> 4;

    f32x4 acc[4][4] = {};

    for (int k0 = 0; k0 < K; k0 += 32) {
#pragma unroll
        for (int p = 0; p < 4; p++) {
            int row = r + p * 32;
            int am  = m0 + row; if (am > M - 1) am = M - 1;   // clamp (garbage rows never stored)
            float4 v = *(const float4*)&A[(size_t)am * K + k0 + c4];
            if (APPLY_BN) {
                float4 s4 = *(const float4*)&sc[k0 + c4];
                float4 h4 = *(const float4*)&sc[HIDC + k0 + c4];
                v.x = fmaxf(fmaf(v.x, s4.x, h4.x), 0.0f);
                v.y = fmaxf(fmaf(v.y, s4.y, h4.y), 0.0f);
                v.z = fmaxf(fmaf(v.z, s4.z, h4.z), 0.0f);
                v.w = fmaxf(fmaf(v.w, s4.w, h4.w), 0.0f);
            }
            As[row][c4 + 0] = (bf16_t)v.x; As[row][c4 + 1] = (bf16_t)v.y;
            As[row][c4 + 2] = (bf16_t)v.z; As[row][c4 + 3] = (bf16_t)v.w;
            float4 w = *(const float4*)&Bsel[(size_t)row * K + k0 + c4];
            Bs[row][c4 + 0] = (bf16_t)w.x; Bs[row][c4 + 1] = (bf16_t)w.y;
            Bs[row][c4 + 2] = (bf16_t)w.z; Bs[row][c4 + 3] = (bf16_t)w.w;
        }
        __syncthreads();

        bf16x8 af[4], bfr[4];
#pragma unroll
        for (int i = 0; i < 4; i++)
            af[i] = *(const bf16x8*)&As[wm + i * 16 + l16][quad * 8];
#pragma unroll
        for (int j = 0; j < 4; j++)
            bfr[j] = *(const bf16x8*)&Bs[wn + j * 16 + l16][quad * 8];
#pragma unroll
        for (int i = 0; i < 4; i++)
#pragma unroll
            for (int j = 0; j < 4; j++)
                acc[i][j] = mfma_16x16x32_bf16(af[i], bfr[j], acc[i][j]);
        __syncthreads();
    }

    // C/D layout (m89-verified): col = lane&15, row = quad*4 + reg
#pragma unroll
    for (int i = 0; i < 4; i++) {
        int rowb = m0 + wm + i * 16 + quad * 4;
#pragma unroll
        for (int j = 0; j < 4; j++) {
            int colh = wn + j * 16 + l16;   // 0..127 within the half
#pragma unroll
            for (int rr = 0; rr < 4; rr++) {
                int row = rowb + rr;
                if (row < M) {
                    if (blockIdx.y == 0) Cl[(size_t)row * HIDC + colh] = (bf16_t)acc[i][j][rr];
                    else                 Cr[(size_t)row * HIDC + colh] = acc[i][j][rr];
                }
            }
        }
    }
}

// ---------- CSR build ----------
__global__ void degi_kernel(const int* __restrict__ ei, int* __restrict__ degi) {
    int e = blockIdx.x * blockDim.x + threadIdx.x;
    if (e < N_EDGESC) atomicAdd(&degi[ei[N_EDGESC + e]], 1);
}

// single block, 1024 threads: chunked exclusive scan of degi -> rowptr, cursor
__global__ __launch_bounds__(1024) void scan_kernel(const int* __restrict__ degi,
                                                    int* __restrict__ rowptr,
                                                    int* __restrict__ cursor)
{
    __shared__ int part[1024];
    const int t = threadIdx.x;
    const int CH = (N_NODESC + 1023) / 1024;   // 49
    const int base = t * CH;
    int sum = 0;
    for (int i = 0; i < CH; i++) {
        int idx = base + i;
        if (idx < N_NODESC) sum += degi[idx];
    }
    part[t] = sum;
    __syncthreads();
    for (int off = 1; off < 1024; off <<= 1) {
        int v = (t >= off) ? part[t - off] : 0;
        __syncthreads();
        part[t] += v;
        __syncthreads();
    }
    int run = part[t] - sum;   // exclusive offset of this thread's chunk
    for (int i = 0; i < CH; i++) {
        int idx = base + i;
        if (idx < N_NODESC) {
            int d = degi[idx];
            rowptr[idx] = run;
            cursor[idx] = run;
            run += d;
        }
    }
    if (t == 1023) rowptr[N_NODESC] = part[1023];
}

__global__ void fill_kernel(const int* __restrict__ ei, int* __restrict__ cursor,
                            int* __restrict__ col) {
    int e = blockIdx.x * blockDim.x + threadIdx.x;
    if (e >= N_EDGESC) return;
    int d = ei[N_EDGESC + e];
    int pos = atomicAdd(&cursor[d], 1);
    col[pos] = ei[e];
}

// ---------- fused CSR-gather mean-agg + bias + Pr + BN partial sums ----------
// 8-way edge unroll: 8 independent bf16 row-loads in flight per wave per round.
// BN stats go to NREP replica slots to avoid same-address atomic serialization.
__global__ __launch_bounds__(128) void agg_combine_kernel(const int* __restrict__ rowptr,
                                                          const int* __restrict__ col,
                                                          const bf16_t* __restrict__ Plb,
                                                          const float* __restrict__ Pr,
                                                          const float* __restrict__ bias,
                                                          float* __restrict__ Hpre,
                                                          float* __restrict__ stats, int M)
{
    const int c = threadIdx.x;
    const float b = bias[c];
    float s = 0.f, s2 = 0.f;
    const int n0 = blockIdx.x * NB_AGG;
    for (int rr = 0; rr < NB_AGG; rr++) {
        int n = n0 + rr;
        if (n >= M) break;
        int lo = rowptr[n], hi = rowptr[n + 1];
        float a = 0.f;
        for (int e = lo; e < hi; e += 8) {
            int rem = hi - e;
            int idx[8];
#pragma unroll
            for (int j = 0; j < 8; j++) {
                int ee = e + j; if (ee > hi - 1) ee = hi - 1;
                idx[j] = col[ee];                       // 8 independent broadcast loads
            }
            float v[8];
#pragma unroll
            for (int j = 0; j < 8; j++)
                v[j] = (float)Plb[(size_t)idx[j] * HIDC + c];   // 8 loads in flight
#pragma unroll
            for (int j = 0; j < 8; j++)
                if (j < rem) a += v[j];                 // wave-uniform predicate
        }
        int d = hi - lo;
        float inv = 1.0f / (float)(d > 0 ? d : 1);
        float pre = fmaf(a, inv, b) + Pr[(size_t)n * HIDC + c];
        Hpre[(size_t)n * HIDC + c] = pre;
        s += pre; s2 += pre * pre;
    }
    const int rep = blockIdx.x & (NREP - 1);
    atomicAdd(&stats[rep * 256 + c], s);
    atomicAdd(&stats[rep * 256 + HIDC + c], s2);
}

// fold NREP replicas; stats -> per-channel scale/shift:  y = x*scale + shift
__global__ __launch_bounds__(128) void finalize_kernel(const float* __restrict__ stats,
                                                       const float* __restrict__ g,
                                                       const float* __restrict__ be,
                                                       float* __restrict__ sc, int M)
{
    int c = threadIdx.x;
    float sum = 0.f, sumsq = 0.f;
    for (int r = 0; r < NREP; r++) {
        sum   += stats[r * 256 + c];
        sumsq += stats[r * 256 + HIDC + c];
    }
    float invM = 1.0f / (float)M;
    float mean = sum * invM;
    float var  = sumsq * invM - mean * mean;
    float s = rsqrtf(var + BN_EPSC) * g[c];
    sc[c] = s;
    sc[HIDC + c] = be[c] - mean * s;
}

// pool with BN3 applied per element (transform precedes max; sign-safe)
__global__ __launch_bounds__(128) void pool_kernel(const float* __restrict__ Hpre,
                                                   const float* __restrict__ sc,
                                                   const int* __restrict__ batch,
                                                   float* __restrict__ pooled, int M)
{
    int gph = blockIdx.x;
    int c   = threadIdx.x;
    float s = sc[c], h = sc[HIDC + c];
    int lo = 0, hi = M;
    while (lo < hi) { int m = (lo + hi) >> 1; if (batch[m] < gph) lo = m + 1; else hi = m; }
    int lo2 = lo, hi2 = M;
    while (lo2 < hi2) { int m = (lo2 + hi2) >> 1; if (batch[m] < gph + 1) lo2 = m + 1; else hi2 = m; }
    float mx = -INFINITY;
    for (int rr = lo; rr < lo2; rr++)
        mx = fmaxf(mx, fmaf(Hpre[(size_t)rr * HIDC + c], s, h));
    pooled[gph * HIDC + c] = mx;
}

__global__ __launch_bounds__(128) void final_kernel(const float* __restrict__ pooled,
                                                    const float* __restrict__ W,
                                                    const float* __restrict__ bl,
                                                    float* __restrict__ out)
{
    __shared__ float sp[HIDC];
    int gph = blockIdx.x;
    int t   = threadIdx.x;
    sp[t] = pooled[gph * HIDC + t];
    __syncthreads();
    if (t < NCLSC) {
        float acc = bl[t];
        for (int c = 0; c < HIDC; c++) acc += sp[c] * W[t * HIDC + c];
        out[gph * NCLSC + t] = acc;
    }
}

extern "C" void kernel_launch(void* const* d_in, const int* in_sizes, int n_in,
                              void* d_out, int out_size, void* d_ws, size_t ws_size,
                              hipStream_t stream)
{
    const float* x     = (const float*)d_in[0];
    const int*   ei    = (const int*)d_in[1];
    const int*   batch = (const int*)d_in[2];
    const float* W1l = (const float*)d_in[3];
    const float* b1  = (const float*)d_in[4];
    const float* W1r = (const float*)d_in[5];
    const float* g1  = (const float*)d_in[6];
    const float* be1 = (const float*)d_in[7];
    const float* W2l = (const float*)d_in[8];
    const float* b2  = (const float*)d_in[9];
    const float* W2r = (const float*)d_in[10];
    const float* g2  = (const float*)d_in[11];
    const float* be2 = (const float*)d_in[12];
    const float* W3l = (const float*)d_in[13];
    const float* b3  = (const float*)d_in[14];
    const float* W3r = (const float*)d_in[15];
    const float* g3  = (const float*)d_in[16];
    const float* be3 = (const float*)d_in[17];
    const float* Wlin = (const float*)d_in[18];
    const float* blin = (const float*)d_in[19];

    const int M = N_NODESC;

    // workspace carve (all 16B-aligned: sizes are multiples of 16)
    char* w = (char*)d_ws;
    bf16_t* Plb  = (bf16_t*)w;  w += (size_t)M * HIDC * 2;   // 12.8 MB
    float* Pr    = (float*)w;   w += (size_t)M * HIDC * 4;   // 25.6 MB
    float* Hpre  = (float*)w;   w += (size_t)M * HIDC * 4;   // 25.6 MB
    int*   rowptr= (int*)w;     w += (size_t)(M + 16) * 4;
    int*   col   = (int*)w;     w += (size_t)N_EDGESC * 4;
    int*   cursor= (int*)w;     w += (size_t)M * 4;
    int*   degi  = (int*)w;     w += (size_t)M * 4;
    float* stats = (float*)w;   w += (size_t)NREP * 256 * 4; // 64 KB replicas
    float* sc    = (float*)w;   w += 256 * 4;
    float* pooled= (float*)w;   w += (size_t)N_GRAPHSC * HIDC * 4;

    const dim3 gemm_grid((M + 127) / 128, 2);
    const int agg_blocks = (M + NB_AGG - 1) / NB_AGG;
    const size_t stats_bytes = (size_t)NREP * 256 * 4;

    // ---- CSR build (per call: ws is re-poisoned) ----
    hipMemsetAsync(degi, 0, (size_t)M * 4, stream);
    degi_kernel<<<(N_EDGESC + 255) / 256, 256, 0, stream>>>(ei, degi);
    scan_kernel<<<1, 1024, 0, stream>>>(degi, rowptr, cursor);
    fill_kernel<<<(N_EDGESC + 255) / 256, 256, 0, stream>>>(ei, cursor, col);

    // ---- layer 1 (K = 768, no BN on input) ----
    gemm_kernel<false><<<gemm_grid, 256, 0, stream>>>(x, W1l, W1r, nullptr, Plb, Pr, M, IN_DIMC);
    hipMemsetAsync(stats, 0, stats_bytes, stream);
    agg_combine_kernel<<<agg_blocks, 128, 0, stream>>>(rowptr, col, Plb, Pr, b1, Hpre, stats, M);
    finalize_kernel<<<1, 128, 0, stream>>>(stats, g1, be1, sc, M);

    // ---- layer 2 (K = 128, BN1+ReLU fused into A-staging) ----
    gemm_kernel<true><<<gemm_grid, 256, 0, stream>>>(Hpre, W2l, W2r, sc, Plb, Pr, M, HIDC);
    hipMemsetAsync(stats, 0, stats_bytes, stream);
    agg_combine_kernel<<<agg_blocks, 128, 0, stream>>>(rowptr, col, Plb, Pr, b2, Hpre, stats, M);
    finalize_kernel<<<1, 128, 0, stream>>>(stats, g2, be2, sc, M);

    // ---- layer 3 (K = 128, BN2+ReLU fused into A-staging) ----
    gemm_kernel<true><<<gemm_grid, 256, 0, stream>>>(Hpre, W3l, W3r, sc, Plb, Pr, M, HIDC);
    hipMemsetAsync(stats, 0, stats_bytes, stream);
    agg_combine_kernel<<<agg_blocks, 128, 0, stream>>>(rowptr, col, Plb, Pr, b3, Hpre, stats, M);
    finalize_kernel<<<1, 128, 0, stream>>>(stats, g3, be3, sc, M);

    // ---- pool (BN3 fused) + head ----
    pool_kernel<<<N_GRAPHSC, 128, 0, stream>>>(Hpre, sc, batch, pooled, M);
    final_kernel<<<N_GRAPHSC, 128, 0, stream>>>(pooled, Wlin, blin, (float*)d_out);
}

// Round 5
// 595.226 us; speedup vs baseline: 2.1786x; 1.1953x over previous
//
#include <hip/hip_runtime.h>

#define N_NODESC 50000
#define N_EDGESC 400000
#define N_GRAPHSC 128
#define IN_DIMC 768
#define HIDC 128
#define NCLSC 11
#define BN_EPSC 1e-5f
#define NB_AGG 8
#define NREP 64   // stats atomic replicas: 6250 blocks / 64 -> ~98-deep chains per address
#define SCAN_NB ((N_NODESC + 255) / 256)   // 196 blocks for the hierarchical scan

typedef __bf16 bf16_t;
typedef __bf16 bf16x8 __attribute__((ext_vector_type(8)));
typedef float f32x4 __attribute__((ext_vector_type(4)));

__device__ inline f32x4 mfma_16x16x32_bf16(bf16x8 a, bf16x8 b, f32x4 c) {
    return __builtin_amdgcn_mfma_f32_16x16x32_bf16(a, b, c, 0, 0, 0);
}

// [Cl | Cr] = BN?(A)[M,K] @ [Bl;Br]^T.  A fp32 row-major; Bl/Br [128,K] fp32.
// blockIdx.y==0 -> writes Cl as bf16 [M,128] (aggregation operand);
// blockIdx.y==1 -> writes Cr as fp32 [M,128] (residual/self term).
// APPLY_BN: A-staging applies relu(a*scale[ch]+shift[ch]) with ch = column of A.
template<bool APPLY_BN>
__global__ __launch_bounds__(256) void gemm_kernel(const float* __restrict__ A,
                                                   const float* __restrict__ Bl,
                                                   const float* __restrict__ Br,
                                                   const float* __restrict__ sc,
                                                   bf16_t* __restrict__ Cl,
                                                   float* __restrict__ Cr, int M, int K)
{
    __shared__ bf16_t As[128][40];   // pad 32->40: 16B-aligned b128 reads, 2-way banks (free)
    __shared__ bf16_t Bs[128][40];

    const int t  = threadIdx.x;
    const int m0 = blockIdx.x * 128;
    const float* Bsel = (blockIdx.y == 0) ? Bl : Br;

    const int r  = t >> 3;         // staging row 0..31 (+p*32)
    const int c4 = (t & 7) * 4;    // staging col 0,4,...,28

    const int wid  = t >> 6;
    const int lane = t & 63;
    const int wm   = (wid >> 1) * 64;
    const int wn   = (wid & 1) * 64;
    const int l16  = lane & 15;
    const int quad = lane >> 4;

    f32x4 acc[4][4] = {};

    for (int k0 = 0; k0 < K; k0 += 32) {
#pragma unroll
        for (int p = 0; p < 4; p++) {
            int row = r + p * 32;
            int am  = m0 + row; if (am > M - 1) am = M - 1;   // clamp (garbage rows never stored)
            float4 v = *(const float4*)&A[(size_t)am * K + k0 + c4];
            if (APPLY_BN) {
                float4 s4 = *(const float4*)&sc[k0 + c4];
                float4 h4 = *(const float4*)&sc[HIDC + k0 + c4];
                v.x = fmaxf(fmaf(v.x, s4.x, h4.x), 0.0f);
                v.y = fmaxf(fmaf(v.y, s4.y, h4.y), 0.0f);
                v.z = fmaxf(fmaf(v.z, s4.z, h4.z), 0.0f);
                v.w = fmaxf(fmaf(v.w, s4.w, h4.w), 0.0f);
            }
            As[row][c4 + 0] = (bf16_t)v.x; As[row][c4 + 1] = (bf16_t)v.y;
            As[row][c4 + 2] = (bf16_t)v.z; As[row][c4 + 3] = (bf16_t)v.w;
            float4 w = *(const float4*)&Bsel[(size_t)row * K + k0 + c4];
            Bs[row][c4 + 0] = (bf16_t)w.x; Bs[row][c4 + 1] = (bf16_t)w.y;
            Bs[row][c4 + 2] = (bf16_t)w.z; Bs[row][c4 + 3] = (bf16_t)w.w;
        }
        __syncthreads();

        bf16x8 af[4], bfr[4];
#pragma unroll
        for (int i = 0; i < 4; i++)
            af[i] = *(const bf16x8*)&As[wm + i * 16 + l16][quad * 8];
#pragma unroll
        for (int j = 0; j < 4; j++)
            bfr[j] = *(const bf16x8*)&Bs[wn + j * 16 + l16][quad * 8];
#pragma unroll
        for (int i = 0; i < 4; i++)
#pragma unroll
            for (int j = 0; j < 4; j++)
                acc[i][j] = mfma_16x16x32_bf16(af[i], bfr[j], acc[i][j]);
        __syncthreads();
    }

    // C/D layout (m89-verified): col = lane&15, row = quad*4 + reg
#pragma unroll
    for (int i = 0; i < 4; i++) {
        int rowb = m0 + wm + i * 16 + quad * 4;
#pragma unroll
        for (int j = 0; j < 4; j++) {
            int colh = wn + j * 16 + l16;   // 0..127 within the half
#pragma unroll
            for (int rr = 0; rr < 4; rr++) {
                int row = rowb + rr;
                if (row < M) {
                    if (blockIdx.y == 0) Cl[(size_t)row * HIDC + colh] = (bf16_t)acc[i][j][rr];
                    else                 Cr[(size_t)row * HIDC + colh] = acc[i][j][rr];
                }
            }
        }
    }
}

// ---------- CSR build ----------
__global__ void degi_kernel(const int* __restrict__ ei, int* __restrict__ degi) {
    int e = blockIdx.x * blockDim.x + threadIdx.x;
    if (e < N_EDGESC) atomicAdd(&degi[ei[N_EDGESC + e]], 1);
}

// hierarchical scan, phase 1: per-block exclusive scan of 256 elems + block total
__global__ __launch_bounds__(256) void scan1_kernel(const int* __restrict__ degi,
                                                    int* __restrict__ local,
                                                    int* __restrict__ partials)
{
    __shared__ int tmp[256];
    const int t = threadIdx.x;
    const int i = blockIdx.x * 256 + t;
    int v = (i < N_NODESC) ? degi[i] : 0;
    tmp[t] = v;
    __syncthreads();
    for (int off = 1; off < 256; off <<= 1) {
        int u = (t >= off) ? tmp[t - off] : 0;
        __syncthreads();
        tmp[t] += u;
        __syncthreads();
    }
    if (i < N_NODESC) local[i] = tmp[t] - v;          // exclusive-in-block
    if (t == 255) partials[blockIdx.x] = tmp[255];    // block total
}

// phase 2: single small block scans the 196 partials (exclusive, in place)
__global__ __launch_bounds__(256) void scan2_kernel(int* __restrict__ partials)
{
    __shared__ int tmp[256];
    const int t = threadIdx.x;
    int v = (t < SCAN_NB) ? partials[t] : 0;
    tmp[t] = v;
    __syncthreads();
    for (int off = 1; off < 256; off <<= 1) {
        int u = (t >= off) ? tmp[t - off] : 0;
        __syncthreads();
        tmp[t] += u;
        __syncthreads();
    }
    if (t < SCAN_NB) partials[t] = tmp[t] - v;        // exclusive block offsets
}

// phase 3: add block offset, emit rowptr + cursor (+ static total)
__global__ __launch_bounds__(256) void scan3_kernel(const int* __restrict__ local,
                                                    const int* __restrict__ partials,
                                                    int* __restrict__ rowptr,
                                                    int* __restrict__ cursor)
{
    const int i = blockIdx.x * 256 + threadIdx.x;
    if (i < N_NODESC) {
        int r = local[i] + partials[blockIdx.x];
        rowptr[i] = r;
        cursor[i] = r;
    }
    if (i == 0) rowptr[N_NODESC] = N_EDGESC;          // total in-degree == edge count
}

__global__ void fill_kernel(const int* __restrict__ ei, int* __restrict__ cursor,
                            int* __restrict__ col) {
    int e = blockIdx.x * blockDim.x + threadIdx.x;
    if (e >= N_EDGESC) return;
    int d = ei[N_EDGESC + e];
    int pos = atomicAdd(&cursor[d], 1);
    col[pos] = ei[e];
}

// ---------- fused CSR-gather mean-agg + bias + Pr + BN partial sums ----------
// 8-way edge unroll: 8 independent bf16 row-loads in flight per wave per round.
// BN stats go to NREP replica slots to avoid same-address atomic serialization.
__global__ __launch_bounds__(128) void agg_combine_kernel(const int* __restrict__ rowptr,
                                                          const int* __restrict__ col,
                                                          const bf16_t* __restrict__ Plb,
                                                          const float* __restrict__ Pr,
                                                          const float* __restrict__ bias,
                                                          float* __restrict__ Hpre,
                                                          float* __restrict__ stats, int M)
{
    const int c = threadIdx.x;
    const float b = bias[c];
    float s = 0.f, s2 = 0.f;
    const int n0 = blockIdx.x * NB_AGG;
    for (int rr = 0; rr < NB_AGG; rr++) {
        int n = n0 + rr;
        if (n >= M) break;
        int lo = rowptr[n], hi = rowptr[n + 1];
        float a = 0.f;
        for (int e = lo; e < hi; e += 8) {
            int rem = hi - e;
            int idx[8];
#pragma unroll
            for (int j = 0; j < 8; j++) {
                int ee = e + j; if (ee > hi - 1) ee = hi - 1;
                idx[j] = col[ee];                       // 8 independent broadcast loads
            }
            float v[8];
#pragma unroll
            for (int j = 0; j < 8; j++)
                v[j] = (float)Plb[(size_t)idx[j] * HIDC + c];   // 8 loads in flight
#pragma unroll
            for (int j = 0; j < 8; j++)
                if (j < rem) a += v[j];                 // wave-uniform predicate
        }
        int d = hi - lo;
        float inv = 1.0f / (float)(d > 0 ? d : 1);
        float pre = fmaf(a, inv, b) + Pr[(size_t)n * HIDC + c];
        Hpre[(size_t)n * HIDC + c] = pre;
        s += pre; s2 += pre * pre;
    }
    const int rep = blockIdx.x & (NREP - 1);
    atomicAdd(&stats[rep * 256 + c], s);
    atomicAdd(&stats[rep * 256 + HIDC + c], s2);
}

// fold NREP replicas; stats -> per-channel scale/shift:  y = x*scale + shift
__global__ __launch_bounds__(128) void finalize_kernel(const float* __restrict__ stats,
                                                       const float* __restrict__ g,
                                                       const float* __restrict__ be,
                                                       float* __restrict__ sc, int M)
{
    int c = threadIdx.x;
    float sum = 0.f, sumsq = 0.f;
    for (int r = 0; r < NREP; r++) {
        sum   += stats[r * 256 + c];
        sumsq += stats[r * 256 + HIDC + c];
    }
    float invM = 1.0f / (float)M;
    float mean = sum * invM;
    float var  = sumsq * invM - mean * mean;
    float s = rsqrtf(var + BN_EPSC) * g[c];
    sc[c] = s;
    sc[HIDC + c] = be[c] - mean * s;
}

// pool with BN3 applied per element (transform precedes max; sign-safe)
__global__ __launch_bounds__(128) void pool_kernel(const float* __restrict__ Hpre,
                                                   const float* __restrict__ sc,
                                                   const int* __restrict__ batch,
                                                   float* __restrict__ pooled, int M)
{
    int gph = blockIdx.x;
    int c   = threadIdx.x;
    float s = sc[c], h = sc[HIDC + c];
    int lo = 0, hi = M;
    while (lo < hi) { int m = (lo + hi) >> 1; if (batch[m] < gph) lo = m + 1; else hi = m; }
    int lo2 = lo, hi2 = M;
    while (lo2 < hi2) { int m = (lo2 + hi2) >> 1; if (batch[m] < gph + 1) lo2 = m + 1; else hi2 = m; }
    float mx = -INFINITY;
    for (int rr = lo; rr < lo2; rr++)
        mx = fmaxf(mx, fmaf(Hpre[(size_t)rr * HIDC + c], s, h));
    pooled[gph * HIDC + c] = mx;
}

__global__ __launch_bounds__(128) void final_kernel(const float* __restrict__ pooled,
                                                    const float* __restrict__ W,
                                                    const float* __restrict__ bl,
                                                    float* __restrict__ out)
{
    __shared__ float sp[HIDC];
    int gph = blockIdx.x;
    int t   = threadIdx.x;
    sp[t] = pooled[gph * HIDC + t];
    __syncthreads();
    if (t < NCLSC) {
        float acc = bl[t];
        for (int c = 0; c < HIDC; c++) acc += sp[c] * W[t * HIDC + c];
        out[gph * NCLSC + t] = acc;
    }
}

extern "C" void kernel_launch(void* const* d_in, const int* in_sizes, int n_in,
                              void* d_out, int out_size, void* d_ws, size_t ws_size,
                              hipStream_t stream)
{
    const float* x     = (const float*)d_in[0];
    const int*   ei    = (const int*)d_in[1];
    const int*   batch = (const int*)d_in[2];
    const float* W1l = (const float*)d_in[3];
    const float* b1  = (const float*)d_in[4];
    const float* W1r = (const float*)d_in[5];
    const float* g1  = (const float*)d_in[6];
    const float* be1 = (const float*)d_in[7];
    const float* W2l = (const float*)d_in[8];
    const float* b2  = (const float*)d_in[9];
    const float* W2r = (const float*)d_in[10];
    const float* g2  = (const float*)d_in[11];
    const float* be2 = (const float*)d_in[12];
    const float* W3l = (const float*)d_in[13];
    const float* b3  = (const float*)d_in[14];
    const float* W3r = (const float*)d_in[15];
    const float* g3  = (const float*)d_in[16];
    const float* be3 = (const float*)d_in[17];
    const float* Wlin = (const float*)d_in[18];
    const float* blin = (const float*)d_in[19];

    const int M = N_NODESC;

    // workspace carve (all 16B-aligned: sizes are multiples of 16)
    char* w = (char*)d_ws;
    bf16_t* Plb  = (bf16_t*)w;  w += (size_t)M * HIDC * 2;   // 12.8 MB
    float* Pr    = (float*)w;   w += (size_t)M * HIDC * 4;   // 25.6 MB
    float* Hpre  = (float*)w;   w += (size_t)M * HIDC * 4;   // 25.6 MB
    int*   rowptr= (int*)w;     w += (size_t)(M + 16) * 4;
    int*   col   = (int*)w;     w += (size_t)N_EDGESC * 4;
    int*   cursor= (int*)w;     w += (size_t)M * 4;
    int*   degi  = (int*)w;     w += (size_t)M * 4;
    int*   slocal= (int*)w;     w += (size_t)M * 4;
    int*   spart = (int*)w;     w += 256 * 4;
    float* stats = (float*)w;   w += (size_t)NREP * 256 * 4; // 64 KB replicas
    float* sc    = (float*)w;   w += 256 * 4;
    float* pooled= (float*)w;   w += (size_t)N_GRAPHSC * HIDC * 4;

    const dim3 gemm_grid((M + 127) / 128, 2);
    const int agg_blocks = (M + NB_AGG - 1) / NB_AGG;
    const size_t stats_bytes = (size_t)NREP * 256 * 4;

    // ---- CSR build (per call: ws is re-poisoned) ----
    hipMemsetAsync(degi, 0, (size_t)M * 4, stream);
    degi_kernel<<<(N_EDGESC + 255) / 256, 256, 0, stream>>>(ei, degi);
    scan1_kernel<<<SCAN_NB, 256, 0, stream>>>(degi, slocal, spart);
    scan2_kernel<<<1, 256, 0, stream>>>(spart);
    scan3_kernel<<<SCAN_NB, 256, 0, stream>>>(slocal, spart, rowptr, cursor);
    fill_kernel<<<(N_EDGESC + 255) / 256, 256, 0, stream>>>(ei, cursor, col);

    // ---- layer 1 (K = 768, no BN on input) ----
    gemm_kernel<false><<<gemm_grid, 256, 0, stream>>>(x, W1l, W1r, nullptr, Plb, Pr, M, IN_DIMC);
    hipMemsetAsync(stats, 0, stats_bytes, stream);
    agg_combine_kernel<<<agg_blocks, 128, 0, stream>>>(rowptr, col, Plb, Pr, b1, Hpre, stats, M);
    finalize_kernel<<<1, 128, 0, stream>>>(stats, g1, be1, sc, M);

    // ---- layer 2 (K = 128, BN1+ReLU fused into A-staging) ----
    gemm_kernel<true><<<gemm_grid, 256, 0, stream>>>(Hpre, W2l, W2r, sc, Plb, Pr, M, HIDC);
    hipMemsetAsync(stats, 0, stats_bytes, stream);
    agg_combine_kernel<<<agg_blocks, 128, 0, stream>>>(rowptr, col, Plb, Pr, b2, Hpre, stats, M);
    finalize_kernel<<<1, 128, 0, stream>>>(stats, g2, be2, sc, M);

    // ---- layer 3 (K = 128, BN2+ReLU fused into A-staging) ----
    gemm_kernel<true><<<gemm_grid, 256, 0, stream>>>(Hpre, W3l, W3r, sc, Plb, Pr, M, HIDC);
    hipMemsetAsync(stats, 0, stats_bytes, stream);
    agg_combine_kernel<<<agg_blocks, 128, 0, stream>>>(rowptr, col, Plb, Pr, b3, Hpre, stats, M);
    finalize_kernel<<<1, 128, 0, stream>>>(stats, g3, be3, sc, M);

    // ---- pool (BN3 fused) + head ----
    pool_kernel<<<N_GRAPHSC, 128, 0, stream>>>(Hpre, sc, batch, pooled, M);
    final_kernel<<<N_GRAPHSC, 128, 0, stream>>>(pooled, Wlin, blin, (float*)d_out);
}